// Round 1
// baseline (404.712 us; speedup 1.0000x reference)
//
#include <hip/hip_runtime.h>
#include <math.h>

#define NVEC 32768   // 32*32*32 vectors
#define NE   1024    // codebook entries
#define ED   64      // embedding dim
#define TOT  2097152 // NVEC*ED total z elements
#define NCHUNK 8     // code chunks inside k_dist
#define CHUNK  128   // codes per chunk
#define MT     64    // vectors per k_dist block

// d_out offsets (in floats): loss | z_q_st | perplexity | min_encodings | idx
#define O_LOSS   0
#define O_ZQ     1
#define O_PERP   2097153
#define O_MINENC 2097154
#define O_IDX    35651586

// d_ws offsets (in floats). k_pre zeroes cnt+sumenc (atomic accumulators) and
// out[O_LOSS]; esq is fully written by k_pre before k_dist reads it.
#define W_PIDX   0        // [32768] final idx (int), written by k_dist
#define W_CS     32768    // [1024] int counts (atomic)
#define W_SUMENC 33792    // [1024*64] float (atomic)
#define W_NEWEMB 99328    // [1024*64]
#define W_ESQ    164864   // [1024] ||e||^2, exact np-pairwise

// R14: k_sumenc (O(NE*N) ballot-scan, latency-chain bound) deleted. Cluster
// stats now scatter out of k_dist's tail: the block already holds 2*z for its
// 64 vectors in s_a (0.5x recovers z exactly) and the per-vector argmin.
// unsafeAtomicAdd -> HW global_atomic_add_f32 (plain float atomicAdd would be
// a CAS loop without -munsafe-fp-atomics). esq hoisted to k_pre with the
// IDENTICAL fp op order -> d bit-identical -> idx bit-identical. k_fin folded
// into k_zq via atomic loss accumulation (per-partial scale 2^-23 is exact).

// blocks 0..64: zero cnt+sumenc (66560 floats = 16640 float4) + out[O_LOSS].
// blocks 65..68: esq[code] with k_dist-R13's exact np-pairwise rounding.
__global__ void __launch_bounds__(256) k_pre(const float* __restrict__ emb,
                                             float* __restrict__ ws,
                                             float* __restrict__ out) {
    int b = blockIdx.x;
    if (b < 65) {
        int i = b * 256 + threadIdx.x;  // 0..16639, exactly 65*256
        float4 zv; zv.x = 0.f; zv.y = 0.f; zv.z = 0.f; zv.w = 0.f;
        *(float4*)(ws + W_CS + i * 4) = zv;
        if (b == 0 && threadIdx.x == 0) out[O_LOSS] = 0.f;
    } else {
        int code = (b - 65) * 256 + threadIdx.x;  // 4*256 = 1024
        const float* ep = emb + (size_t)code * ED;
        float r[8];
#pragma unroll
        for (int j = 0; j < 8; ++j) r[j] = __fmul_rn(ep[j], ep[j]);
#pragma unroll
        for (int i = 8; i < 64; i += 8)
#pragma unroll
            for (int j = 0; j < 8; ++j)
                r[j] = __fadd_rn(r[j], __fmul_rn(ep[i + j], ep[i + j]));
        ws[W_ESQ + code] = __fadd_rn(
            __fadd_rn(__fadd_rn(r[0], r[1]), __fadd_rn(r[2], r[3])),
            __fadd_rn(__fadd_rn(r[4], r[5]), __fadd_rn(r[6], r[7])));
    }
}

__global__ void __launch_bounds__(256, 3) k_dist(const float* __restrict__ z,
                                                 const float* __restrict__ emb,
                                                 const float* __restrict__ esq_g,
                                                 int* __restrict__ fidx,
                                                 int* __restrict__ cnt,
                                                 float* __restrict__ sumenc,
                                                 float* __restrict__ out) {
    __shared__ __align__(16) float s_a[64 * 64];    // [c][m] : 2*z (16 KB)
    __shared__ __align__(16) float s_b[64 * 132];   // [c][k-swizzled] (33 KB)
    __shared__ float s_esq[CHUNK];
    __shared__ float s_zsq[MT];
    __shared__ int s_bi[MT];

    int tid = threadIdx.x;
    int n0 = blockIdx.x * MT;
    int b = n0 >> 10, hw0 = n0 & 1023;  // MT=64 tile never crosses a b boundary
    const float* zb = z + b * 65536 + hw0;

    // Stage A once: 64c x 64m = 1024 float4, coalesced; store 2*z (exact x2)
#pragma unroll
    for (int j = 0; j < 4; ++j) {
        int f4i = j * 256 + tid;
        int c = f4i >> 4, pos = (f4i & 15) * 4;
        float4 v = *(const float4*)(zb + (c << 10) + pos);
        v.x = __fmul_rn(2.0f, v.x);
        v.y = __fmul_rn(2.0f, v.y);
        v.z = __fmul_rn(2.0f, v.z);
        v.w = __fmul_rn(2.0f, v.w);
        *(float4*)(s_a + c * 64 + pos) = v;
    }
    __syncthreads();

    // zsq once (threads 0..63): np-pairwise over z; from (2z): exact x0.25.
    if (tid < MT) {
        float r[8];
#pragma unroll
        for (int j = 0; j < 8; ++j) {
            float v = s_a[j * 64 + tid];
            r[j] = __fmul_rn(v, v);
        }
#pragma unroll
        for (int i = 8; i < 64; i += 8)
#pragma unroll
            for (int j = 0; j < 8; ++j) {
                float v = s_a[(i + j) * 64 + tid];
                r[j] = __fadd_rn(r[j], __fmul_rn(v, v));
            }
        s_zsq[tid] = __fmul_rn(0.25f, __fadd_rn(
            __fadd_rn(__fadd_rn(r[0], r[1]), __fadd_rn(r[2], r[3])),
            __fadd_rn(__fadd_rn(r[4], r[5]), __fadd_rn(r[6], r[7]))));
    }
    __syncthreads();

    int mi = tid & 15, ki = tid >> 4;
    int mbase = mi * 4, kbase = ki * 8;
    float zs[4];
#pragma unroll
    for (int mu = 0; mu < 4; ++mu) zs[mu] = s_zsq[mbase + mu];

    float bd[4];
    int bix[4];
#pragma unroll
    for (int mu = 0; mu < 4; ++mu) { bd[mu] = 3.4e38f; bix[mu] = kbase; }

    for (int q = 0; q < NCHUNK; ++q) {
        int k0 = q * CHUNK;
        __syncthreads();  // previous chunk's readers of s_b/s_esq are done
        // Stage B transposed+swizzled: phys quad (k4+c4)&31. Per store
        // instruction k4 is wave-uniform, c4 spans 0..15 -> 32 banks, 2-way.
#pragma unroll
        for (int j = 0; j < 8; ++j) {
            int f4i = j * 256 + tid;
            int kl = f4i >> 4, c4 = f4i & 15;
            float4 v = *(const float4*)(emb + (size_t)(k0 + kl) * ED + c4 * 4);
            int base = ((( kl >> 2) + c4) & 31) * 4 + (kl & 3);
            s_b[(c4 * 4 + 0) * 132 + base] = v.x;
            s_b[(c4 * 4 + 1) * 132 + base] = v.y;
            s_b[(c4 * 4 + 2) * 132 + base] = v.z;
            s_b[(c4 * 4 + 3) * 132 + base] = v.w;
        }
        // esq for this chunk: precomputed by k_pre (bit-identical rounding)
        if (tid < CHUNK) s_esq[tid] = esq_g[k0 + tid];
        __syncthreads();

        float acc[4][8];
#pragma unroll
        for (int mu = 0; mu < 4; ++mu)
#pragma unroll
            for (int ku = 0; ku < 8; ++ku) acc[mu][ku] = 0.f;

#pragma unroll 4
        for (int c = 0; c < 64; ++c) {
            int c4 = c >> 2;
            float4 av = *(const float4*)(s_a + c * 64 + mbase);
            float4 b0 = *(const float4*)(s_b + c * 132 + ((2 * ki + c4) & 31) * 4);
            float4 b1 = *(const float4*)(s_b + c * 132 + ((2 * ki + 1 + c4) & 31) * 4);
#pragma unroll
            for (int mu = 0; mu < 4; ++mu) {
                float a = (&av.x)[mu];
                acc[mu][0] = __fmaf_rn(a, b0.x, acc[mu][0]);
                acc[mu][1] = __fmaf_rn(a, b0.y, acc[mu][1]);
                acc[mu][2] = __fmaf_rn(a, b0.z, acc[mu][2]);
                acc[mu][3] = __fmaf_rn(a, b0.w, acc[mu][3]);
                acc[mu][4] = __fmaf_rn(a, b1.x, acc[mu][4]);
                acc[mu][5] = __fmaf_rn(a, b1.y, acc[mu][5]);
                acc[mu][6] = __fmaf_rn(a, b1.z, acc[mu][6]);
                acc[mu][7] = __fmaf_rn(a, b1.w, acc[mu][7]);
            }
        }

        // d = fl(fl(zsq+esq) - dot2); running per-thread argmin (k ascending)
#pragma unroll
        for (int mu = 0; mu < 4; ++mu)
#pragma unroll
            for (int ku = 0; ku < 8; ++ku) {
                float d = __fsub_rn(__fadd_rn(zs[mu], s_esq[kbase + ku]),
                                    acc[mu][ku]);
                if (d < bd[mu]) { bd[mu] = d; bix[mu] = k0 + kbase + ku; }
            }
    }

    // Merge 16 ki candidates per m with lexicographic (d, i) min ==
    // np.argmin lowest-index-among-minima. Reuse s_b as scratch.
    __syncthreads();
    float* red_d = s_b;               // [16][64]
    int* red_i = (int*)(s_b + 1024);  // [16][64]
#pragma unroll
    for (int mu = 0; mu < 4; ++mu) {
        red_d[ki * 64 + mbase + mu] = bd[mu];
        red_i[ki * 64 + mbase + mu] = bix[mu];
    }
    __syncthreads();
    if (tid < MT) {
        float best = red_d[tid];
        int bi = red_i[tid];
#pragma unroll
        for (int q = 1; q < 16; ++q) {
            float d = red_d[q * 64 + tid];
            int i = red_i[q * 64 + tid];
            if (d < best || (d == best && i < bi)) { best = d; bi = i; }
        }
        fidx[n0 + tid] = bi;
        out[O_IDX + n0 + tid] = (float)bi;
        s_bi[tid] = bi;
        atomicAdd(&cnt[bi], 1);  // int atomic: HW, exact
    }
    __syncthreads();

    // Scatter tail: cluster-stat accumulation. s_a still holds 2*z; 0.5x is
    // exact. Wave w covers dims c = 16w..16w+15; the LDS read s_a[c*64+lane]
    // is 64 consecutive floats (conflict-free). Atomic addresses scatter by
    // code (avg 32-way contention over the whole grid -> fine at L2/MALL).
    {
        int lane = tid & 63, w = tid >> 6;
        int myb = s_bi[lane];
        float* se = sumenc + ((size_t)myb << 6);
#pragma unroll
        for (int i = 0; i < 16; ++i) {
            int c = (w << 4) | i;
            float v = __fmul_rn(0.5f, s_a[(c << 6) + lane]);
            unsafeAtomicAdd(se + c, v);  // HW global_atomic_add_f32
        }
    }
}

// Single block, 1024 threads: EMA cluster-size + ntot/entropy reductions +
// perplexity + codebook update. Counts now arrive as ints (exact in fp32).
__global__ void __launch_bounds__(1024) k_ema(const float* __restrict__ ema_cs,
                                              const float* __restrict__ ema_w,
                                              const int* __restrict__ cnt,
                                              const float* __restrict__ sumenc,
                                              float* __restrict__ newemb,
                                              float* __restrict__ out) {
    int k = threadIdx.x;  // 0..1023 == NE
    float c = (float)cnt[k];
    float ncs = 0.99f * ema_cs[k] + (1.0f - 0.99f) * c;
    float p = c * (1.0f / (float)NVEC);
    float e = p * logf(p + 1e-10f);
    float rn_ = ncs, re_ = e;
#pragma unroll
    for (int o = 32; o > 0; o >>= 1) {
        rn_ += __shfl_down(rn_, o, 64);
        re_ += __shfl_down(re_, o, 64);
    }
    __shared__ float sn[16], se_[16];
    __shared__ float s_n;
    int wave = k >> 6, lane = k & 63;
    if (lane == 0) { sn[wave] = rn_; se_[wave] = re_; }
    __syncthreads();
    if (k == 0) {
        float tn = 0.f, te = 0.f;
#pragma unroll
        for (int w = 0; w < 16; ++w) { tn += sn[w]; te += se_[w]; }
        s_n = tn;
        out[O_PERP] = expf(-te);
    }
    __syncthreads();
    float nt = s_n;
    float csn = (ncs + 1e-5f) / (nt + 1024.0f * 1e-5f) * nt;
    __shared__ float s_csn[NE];
    s_csn[k] = csn;
    __syncthreads();
    for (int t = k; t < NE * ED; t += 1024) {  // coalesced
        float nw = 0.99f * ema_w[t] + (1.0f - 0.99f) * sumenc[t];
        newemb[t] = nw / s_csn[t >> 6];
    }
}

// 2048 blocks x 256 threads: z_q + straight-through + loss + the one-hot rows
// (16 per block). One-hot coverage: row base is = 2 mod 4 floats, so float4 at
// cols 2+4t (t<254) covers 2..1017; t=254 does the 2-col head; t=255 does
// float4 at 1018 + float2 at 1022 -> full 0..1023. Loss finalize fused here:
// per-block partial scaled by 0.25/TOT = 2^-23 (exact) then atomic-added into
// out[O_LOSS] (zeroed by k_pre). Order nondeterminism ~1e-9 abs on loss~0.25.
__global__ void __launch_bounds__(256) k_zq(const float* __restrict__ z,
                                            const int* __restrict__ idx,
                                            const float* __restrict__ newemb,
                                            float* __restrict__ out) {
    __shared__ int sbi[16];
    if (threadIdx.x < 16) sbi[threadIdx.x] = idx[blockIdx.x * 16 + threadIdx.x];
    __syncthreads();

    float local = 0.f;
#pragma unroll
    for (int i = 0; i < 4; ++i) {
        int t = blockIdx.x * 256 + threadIdx.x + i * 524288;
        int b = t >> 16, c = (t >> 10) & 63, hw = t & 1023;
        int n = (b << 10) | hw;
        float e = newemb[idx[n] * ED + c];
        float zv = z[t];
        float diff = e - zv;             // z_q - z
        out[O_ZQ + t] = zv + diff;       // straight-through: z + (z_q - z)
        local = fmaf(diff, diff, local);
    }

    // one-hot rows r0..r0+15
    int t = threadIdx.x;
    int r0 = blockIdx.x * 16;
    for (int r = 0; r < 16; ++r) {
        int rbi = sbi[r];
        float* rp = out + O_MINENC + (size_t)(r0 + r) * NE;
        if (t < 254) {
            int col = 2 + t * 4;
            float4 v;
            v.x = (col == rbi) ? 1.0f : 0.0f;
            v.y = (col + 1 == rbi) ? 1.0f : 0.0f;
            v.z = (col + 2 == rbi) ? 1.0f : 0.0f;
            v.w = (col + 3 == rbi) ? 1.0f : 0.0f;
            *(float4*)(rp + col) = v;
        } else if (t == 254) {
            float2 v;
            v.x = (0 == rbi) ? 1.0f : 0.0f;
            v.y = (1 == rbi) ? 1.0f : 0.0f;
            *(float2*)(rp) = v;
        } else {
            float4 v;
            v.x = (1018 == rbi) ? 1.0f : 0.0f;
            v.y = (1019 == rbi) ? 1.0f : 0.0f;
            v.z = (1020 == rbi) ? 1.0f : 0.0f;
            v.w = (1021 == rbi) ? 1.0f : 0.0f;
            *(float4*)(rp + 1018) = v;
            float2 w;
            w.x = (1022 == rbi) ? 1.0f : 0.0f;
            w.y = (1023 == rbi) ? 1.0f : 0.0f;
            *(float2*)(rp + 1022) = w;
        }
    }

#pragma unroll
    for (int o = 32; o > 0; o >>= 1) local += __shfl_down(local, o, 64);
    __shared__ float sp[4];
    int wave = threadIdx.x >> 6;
    if ((threadIdx.x & 63) == 0) sp[wave] = local;
    __syncthreads();
    if (threadIdx.x == 0)
        unsafeAtomicAdd(out + O_LOSS,
                        ((sp[0] + sp[1]) + (sp[2] + sp[3])) * (0.25f / (float)TOT));
}

extern "C" void kernel_launch(void* const* d_in, const int* in_sizes, int n_in,
                              void* d_out, int out_size, void* d_ws, size_t ws_size,
                              hipStream_t stream) {
    const float* z      = (const float*)d_in[0];
    const float* emb    = (const float*)d_in[1];
    const float* ema_cs = (const float*)d_in[2];
    const float* ema_w  = (const float*)d_in[3];
    float* out = (float*)d_out;
    float* ws  = (float*)d_ws;

    k_pre<<<69, 256, 0, stream>>>(emb, ws, out);
    k_dist<<<512, 256, 0, stream>>>(z, emb, ws + W_ESQ, (int*)(ws + W_PIDX),
                                    (int*)(ws + W_CS), ws + W_SUMENC, out);
    k_ema<<<1, 1024, 0, stream>>>(ema_cs, ema_w, (const int*)(ws + W_CS),
                                  ws + W_SUMENC, ws + W_NEWEMB, out);
    k_zq<<<2048, 256, 0, stream>>>(z, (const int*)(ws + W_PIDX), ws + W_NEWEMB,
                                   out);
}

// Round 2
// 254.712 us; speedup vs baseline: 1.5889x; 1.5889x over previous
//
#include <hip/hip_runtime.h>
#include <math.h>

#define NVEC 32768   // 32*32*32 vectors
#define NE   1024    // codebook entries
#define ED   64      // embedding dim
#define TOT  2097152 // NVEC*ED total z elements
#define NCHUNK 8     // code chunks inside k_dist
#define CHUNK  128   // codes per chunk
#define MT     64    // vectors per k_dist block

// d_out offsets (in floats): loss | z_q_st | perplexity | min_encodings | idx
#define O_LOSS   0
#define O_ZQ     1
#define O_PERP   2097153
#define O_MINENC 2097154
#define O_IDX    35651586

// d_ws offsets (in floats). k_pre zeroes cnt+sumenc (atomic accumulators) and
// out[O_LOSS]; esq is fully written by k_pre before k_dist reads it.
#define W_PIDX   0        // [32768] final idx (int), written by k_dist
#define W_CS     32768    // [1024] int counts (atomic)
#define W_SUMENC 33792    // [1024*64] float (atomic)
#define W_NEWEMB 99328    // [1024*64]
#define W_ESQ    164864   // [1024] ||e||^2, exact np-pairwise

// R15 post-mortem of R14: the scatter tail (lane=vector, dim=iterated) made
// every fp atomic lane hit a DIFFERENT code's line -> 2.1M scattered
// device-scope atomics, WRITE_SIZE 66 MB, k_dist 234us at 16.8% VALUBusy.
// Fix: transpose the tail. Lane=dim, wave iterates vectors: each atomic
// instruction writes sumenc[bi*64 + 0..63] = 256B contiguous (4 lines).
// 32768 coalesced atomic insts total (16x fewer line-ops). The transposed
// z-read would be a 64-way LDS conflict from s_a, so 0.5*z is first staged
// into s_b (free after the argmin merge) at stride 65 (banks (m+c)%32, 2-way
// = free both ways). esq precompute + k_zq loss fusion kept (not implicated).

// blocks 0..64: zero cnt+sumenc (66560 floats = 16640 float4) + out[O_LOSS].
// blocks 65..68: esq[code] with the exact np-pairwise rounding k_dist used.
__global__ void __launch_bounds__(256) k_pre(const float* __restrict__ emb,
                                             float* __restrict__ ws,
                                             float* __restrict__ out) {
    int b = blockIdx.x;
    if (b < 65) {
        int i = b * 256 + threadIdx.x;  // 0..16639, exactly 65*256
        float4 zv; zv.x = 0.f; zv.y = 0.f; zv.z = 0.f; zv.w = 0.f;
        *(float4*)(ws + W_CS + i * 4) = zv;
        if (b == 0 && threadIdx.x == 0) out[O_LOSS] = 0.f;
    } else {
        int code = (b - 65) * 256 + threadIdx.x;  // 4*256 = 1024
        const float* ep = emb + (size_t)code * ED;
        float r[8];
#pragma unroll
        for (int j = 0; j < 8; ++j) r[j] = __fmul_rn(ep[j], ep[j]);
#pragma unroll
        for (int i = 8; i < 64; i += 8)
#pragma unroll
            for (int j = 0; j < 8; ++j)
                r[j] = __fadd_rn(r[j], __fmul_rn(ep[i + j], ep[i + j]));
        ws[W_ESQ + code] = __fadd_rn(
            __fadd_rn(__fadd_rn(r[0], r[1]), __fadd_rn(r[2], r[3])),
            __fadd_rn(__fadd_rn(r[4], r[5]), __fadd_rn(r[6], r[7])));
    }
}

__global__ void __launch_bounds__(256, 3) k_dist(const float* __restrict__ z,
                                                 const float* __restrict__ emb,
                                                 const float* __restrict__ esq_g,
                                                 int* __restrict__ fidx,
                                                 int* __restrict__ cnt,
                                                 float* __restrict__ sumenc,
                                                 float* __restrict__ out) {
    __shared__ __align__(16) float s_a[64 * 64];    // [c][m] : 2*z (16 KB)
    __shared__ __align__(16) float s_b[64 * 132];   // [c][k-swizzled] (33 KB)
    __shared__ float s_esq[CHUNK];
    __shared__ float s_zsq[MT];
    __shared__ int s_bi[MT];

    int tid = threadIdx.x;
    int n0 = blockIdx.x * MT;
    int b = n0 >> 10, hw0 = n0 & 1023;  // MT=64 tile never crosses a b boundary
    const float* zb = z + b * 65536 + hw0;

    // Stage A once: 64c x 64m = 1024 float4, coalesced; store 2*z (exact x2)
#pragma unroll
    for (int j = 0; j < 4; ++j) {
        int f4i = j * 256 + tid;
        int c = f4i >> 4, pos = (f4i & 15) * 4;
        float4 v = *(const float4*)(zb + (c << 10) + pos);
        v.x = __fmul_rn(2.0f, v.x);
        v.y = __fmul_rn(2.0f, v.y);
        v.z = __fmul_rn(2.0f, v.z);
        v.w = __fmul_rn(2.0f, v.w);
        *(float4*)(s_a + c * 64 + pos) = v;
    }
    __syncthreads();

    // zsq once (threads 0..63): np-pairwise over z; from (2z): exact x0.25.
    if (tid < MT) {
        float r[8];
#pragma unroll
        for (int j = 0; j < 8; ++j) {
            float v = s_a[j * 64 + tid];
            r[j] = __fmul_rn(v, v);
        }
#pragma unroll
        for (int i = 8; i < 64; i += 8)
#pragma unroll
            for (int j = 0; j < 8; ++j) {
                float v = s_a[(i + j) * 64 + tid];
                r[j] = __fadd_rn(r[j], __fmul_rn(v, v));
            }
        s_zsq[tid] = __fmul_rn(0.25f, __fadd_rn(
            __fadd_rn(__fadd_rn(r[0], r[1]), __fadd_rn(r[2], r[3])),
            __fadd_rn(__fadd_rn(r[4], r[5]), __fadd_rn(r[6], r[7]))));
    }
    __syncthreads();

    int mi = tid & 15, ki = tid >> 4;
    int mbase = mi * 4, kbase = ki * 8;
    float zs[4];
#pragma unroll
    for (int mu = 0; mu < 4; ++mu) zs[mu] = s_zsq[mbase + mu];

    float bd[4];
    int bix[4];
#pragma unroll
    for (int mu = 0; mu < 4; ++mu) { bd[mu] = 3.4e38f; bix[mu] = kbase; }

    for (int q = 0; q < NCHUNK; ++q) {
        int k0 = q * CHUNK;
        __syncthreads();  // previous chunk's readers of s_b/s_esq are done
        // Stage B transposed+swizzled: phys quad (k4+c4)&31. Per store
        // instruction k4 is wave-uniform, c4 spans 0..15 -> 32 banks, 2-way.
#pragma unroll
        for (int j = 0; j < 8; ++j) {
            int f4i = j * 256 + tid;
            int kl = f4i >> 4, c4 = f4i & 15;
            float4 v = *(const float4*)(emb + (size_t)(k0 + kl) * ED + c4 * 4);
            int base = ((( kl >> 2) + c4) & 31) * 4 + (kl & 3);
            s_b[(c4 * 4 + 0) * 132 + base] = v.x;
            s_b[(c4 * 4 + 1) * 132 + base] = v.y;
            s_b[(c4 * 4 + 2) * 132 + base] = v.z;
            s_b[(c4 * 4 + 3) * 132 + base] = v.w;
        }
        // esq for this chunk: precomputed by k_pre (bit-identical rounding)
        if (tid < CHUNK) s_esq[tid] = esq_g[k0 + tid];
        __syncthreads();

        float acc[4][8];
#pragma unroll
        for (int mu = 0; mu < 4; ++mu)
#pragma unroll
            for (int ku = 0; ku < 8; ++ku) acc[mu][ku] = 0.f;

#pragma unroll 4
        for (int c = 0; c < 64; ++c) {
            int c4 = c >> 2;
            float4 av = *(const float4*)(s_a + c * 64 + mbase);
            float4 b0 = *(const float4*)(s_b + c * 132 + ((2 * ki + c4) & 31) * 4);
            float4 b1 = *(const float4*)(s_b + c * 132 + ((2 * ki + 1 + c4) & 31) * 4);
#pragma unroll
            for (int mu = 0; mu < 4; ++mu) {
                float a = (&av.x)[mu];
                acc[mu][0] = __fmaf_rn(a, b0.x, acc[mu][0]);
                acc[mu][1] = __fmaf_rn(a, b0.y, acc[mu][1]);
                acc[mu][2] = __fmaf_rn(a, b0.z, acc[mu][2]);
                acc[mu][3] = __fmaf_rn(a, b0.w, acc[mu][3]);
                acc[mu][4] = __fmaf_rn(a, b1.x, acc[mu][4]);
                acc[mu][5] = __fmaf_rn(a, b1.y, acc[mu][5]);
                acc[mu][6] = __fmaf_rn(a, b1.z, acc[mu][6]);
                acc[mu][7] = __fmaf_rn(a, b1.w, acc[mu][7]);
            }
        }

        // d = fl(fl(zsq+esq) - dot2); running per-thread argmin (k ascending)
#pragma unroll
        for (int mu = 0; mu < 4; ++mu)
#pragma unroll
            for (int ku = 0; ku < 8; ++ku) {
                float d = __fsub_rn(__fadd_rn(zs[mu], s_esq[kbase + ku]),
                                    acc[mu][ku]);
                if (d < bd[mu]) { bd[mu] = d; bix[mu] = k0 + kbase + ku; }
            }
    }

    // Merge 16 ki candidates per m with lexicographic (d, i) min ==
    // np.argmin lowest-index-among-minima. Reuse s_b as scratch.
    __syncthreads();
    float* red_d = s_b;               // [16][64]
    int* red_i = (int*)(s_b + 1024);  // [16][64]
#pragma unroll
    for (int mu = 0; mu < 4; ++mu) {
        red_d[ki * 64 + mbase + mu] = bd[mu];
        red_i[ki * 64 + mbase + mu] = bix[mu];
    }
    __syncthreads();
    if (tid < MT) {
        float best = red_d[tid];
        int bi = red_i[tid];
#pragma unroll
        for (int q = 1; q < 16; ++q) {
            float d = red_d[q * 64 + tid];
            int i = red_i[q * 64 + tid];
            if (d < best || (d == best && i < bi)) { best = d; bi = i; }
        }
        fidx[n0 + tid] = bi;
        out[O_IDX + n0 + tid] = (float)bi;
        s_bi[tid] = bi;
        atomicAdd(&cnt[bi], 1);  // int atomic: HW, exact
    }
    __syncthreads();  // merge done: s_b free again; s_bi visible

    // Transpose 0.5*z into s_b at stride 65 (m-major). Per instruction:
    // read s_a[c*64+m] lanes m consecutive (free); write banks (m+c)%32
    // (2-way = free). c = j*4 + wave covers 0..63 over 16 iters.
    {
        int m = tid & 63, w4 = tid >> 6;
#pragma unroll
        for (int j = 0; j < 16; ++j) {
            int c = j * 4 + w4;
            s_b[m * 65 + c] = __fmul_rn(0.5f, s_a[c * 64 + m]);
        }
    }
    __syncthreads();

    // Coalesced scatter: wave w handles vectors m = 16w..16w+15. Lane = dim.
    // Each atomic instruction: sumenc[bi*64 + 0..63] = 256B contiguous.
    {
        int lane = tid & 63, w = tid >> 6;
#pragma unroll
        for (int t = 0; t < 16; ++t) {
            int m = (w << 4) | t;
            int bi = s_bi[m];
            float v = s_b[m * 65 + lane];
            unsafeAtomicAdd(sumenc + ((size_t)bi << 6) + lane, v);
        }
    }
}

// Single block, 1024 threads: EMA cluster-size + ntot/entropy reductions +
// perplexity + codebook update. Counts arrive as ints (exact in fp32).
__global__ void __launch_bounds__(1024) k_ema(const float* __restrict__ ema_cs,
                                              const float* __restrict__ ema_w,
                                              const int* __restrict__ cnt,
                                              const float* __restrict__ sumenc,
                                              float* __restrict__ newemb,
                                              float* __restrict__ out) {
    int k = threadIdx.x;  // 0..1023 == NE
    float c = (float)cnt[k];
    float ncs = 0.99f * ema_cs[k] + (1.0f - 0.99f) * c;
    float p = c * (1.0f / (float)NVEC);
    float e = p * logf(p + 1e-10f);
    float rn_ = ncs, re_ = e;
#pragma unroll
    for (int o = 32; o > 0; o >>= 1) {
        rn_ += __shfl_down(rn_, o, 64);
        re_ += __shfl_down(re_, o, 64);
    }
    __shared__ float sn[16], se_[16];
    __shared__ float s_n;
    int wave = k >> 6, lane = k & 63;
    if (lane == 0) { sn[wave] = rn_; se_[wave] = re_; }
    __syncthreads();
    if (k == 0) {
        float tn = 0.f, te = 0.f;
#pragma unroll
        for (int w = 0; w < 16; ++w) { tn += sn[w]; te += se_[w]; }
        s_n = tn;
        out[O_PERP] = expf(-te);
    }
    __syncthreads();
    float nt = s_n;
    float csn = (ncs + 1e-5f) / (nt + 1024.0f * 1e-5f) * nt;
    __shared__ float s_csn[NE];
    s_csn[k] = csn;
    __syncthreads();
    for (int t = k; t < NE * ED; t += 1024) {  // coalesced
        float nw = 0.99f * ema_w[t] + (1.0f - 0.99f) * sumenc[t];
        newemb[t] = nw / s_csn[t >> 6];
    }
}

// 2048 blocks x 256 threads: z_q + straight-through + loss + the one-hot rows
// (16 per block). One-hot coverage: row base is = 2 mod 4 floats, so float4 at
// cols 2+4t (t<254) covers 2..1017; t=254 does the 2-col head; t=255 does
// float4 at 1018 + float2 at 1022 -> full 0..1023. Loss finalize fused here:
// per-block partial scaled by 0.25/TOT = 2^-23 (exact) then atomic-added into
// out[O_LOSS] (zeroed by k_pre). Order nondeterminism ~1e-9 abs on loss~0.25.
__global__ void __launch_bounds__(256) k_zq(const float* __restrict__ z,
                                            const int* __restrict__ idx,
                                            const float* __restrict__ newemb,
                                            float* __restrict__ out) {
    __shared__ int sbi[16];
    if (threadIdx.x < 16) sbi[threadIdx.x] = idx[blockIdx.x * 16 + threadIdx.x];
    __syncthreads();

    float local = 0.f;
#pragma unroll
    for (int i = 0; i < 4; ++i) {
        int t = blockIdx.x * 256 + threadIdx.x + i * 524288;
        int b = t >> 16, c = (t >> 10) & 63, hw = t & 1023;
        int n = (b << 10) | hw;
        float e = newemb[idx[n] * ED + c];
        float zv = z[t];
        float diff = e - zv;             // z_q - z
        out[O_ZQ + t] = zv + diff;       // straight-through: z + (z_q - z)
        local = fmaf(diff, diff, local);
    }

    // one-hot rows r0..r0+15
    int t = threadIdx.x;
    int r0 = blockIdx.x * 16;
    for (int r = 0; r < 16; ++r) {
        int rbi = sbi[r];
        float* rp = out + O_MINENC + (size_t)(r0 + r) * NE;
        if (t < 254) {
            int col = 2 + t * 4;
            float4 v;
            v.x = (col == rbi) ? 1.0f : 0.0f;
            v.y = (col + 1 == rbi) ? 1.0f : 0.0f;
            v.z = (col + 2 == rbi) ? 1.0f : 0.0f;
            v.w = (col + 3 == rbi) ? 1.0f : 0.0f;
            *(float4*)(rp + col) = v;
        } else if (t == 254) {
            float2 v;
            v.x = (0 == rbi) ? 1.0f : 0.0f;
            v.y = (1 == rbi) ? 1.0f : 0.0f;
            *(float2*)(rp) = v;
        } else {
            float4 v;
            v.x = (1018 == rbi) ? 1.0f : 0.0f;
            v.y = (1019 == rbi) ? 1.0f : 0.0f;
            v.z = (1020 == rbi) ? 1.0f : 0.0f;
            v.w = (1021 == rbi) ? 1.0f : 0.0f;
            *(float4*)(rp + 1018) = v;
            float2 w;
            w.x = (1022 == rbi) ? 1.0f : 0.0f;
            w.y = (1023 == rbi) ? 1.0f : 0.0f;
            *(float2*)(rp + 1022) = w;
        }
    }

#pragma unroll
    for (int o = 32; o > 0; o >>= 1) local += __shfl_down(local, o, 64);
    __shared__ float sp[4];
    int wave = threadIdx.x >> 6;
    if ((threadIdx.x & 63) == 0) sp[wave] = local;
    __syncthreads();
    if (threadIdx.x == 0)
        unsafeAtomicAdd(out + O_LOSS,
                        ((sp[0] + sp[1]) + (sp[2] + sp[3])) * (0.25f / (float)TOT));
}

extern "C" void kernel_launch(void* const* d_in, const int* in_sizes, int n_in,
                              void* d_out, int out_size, void* d_ws, size_t ws_size,
                              hipStream_t stream) {
    const float* z      = (const float*)d_in[0];
    const float* emb    = (const float*)d_in[1];
    const float* ema_cs = (const float*)d_in[2];
    const float* ema_w  = (const float*)d_in[3];
    float* out = (float*)d_out;
    float* ws  = (float*)d_ws;

    k_pre<<<69, 256, 0, stream>>>(emb, ws, out);
    k_dist<<<512, 256, 0, stream>>>(z, emb, ws + W_ESQ, (int*)(ws + W_PIDX),
                                    (int*)(ws + W_CS), ws + W_SUMENC, out);
    k_ema<<<1, 1024, 0, stream>>>(ema_cs, ema_w, (const int*)(ws + W_CS),
                                  ws + W_SUMENC, ws + W_NEWEMB, out);
    k_zq<<<2048, 256, 0, stream>>>(z, (const int*)(ws + W_PIDX), ws + W_NEWEMB,
                                   out);
}